// Round 8
// baseline (152.514 us; speedup 1.0000x reference)
//
#include <hip/hip_runtime.h>
#include <cstdint>
#include <cstddef>

// Mask R-CNN detection post-processing, 3 stream-ordered dispatches:
//   0. memset: zero 81 per-class tickets (324 B)
//   1. nms_mega (648 x 256, block = class k x word w):
//        redundant per-class u64-key stable rank (LDS-local) -> sorted boxes
//        -> IoU bitmatrix word w -> global; then ticket[k]++; the 8th arrival
//        (deadlock-free last-arrival pattern) runs the R7-proven single-wave
//        nz-filtered greedy sweep + top-300 cut + masked-score scatter using
//        its own LDS rank tables. Sweeps overlap other classes' bitmatrix.
//   2. finalize (8 x 512): per-row max/first-argmax (redundant per block),
//        distributed u64-key top-100 rank, output write (R7-proven verbatim).
// Stable sorts via integer keys (softmax scores >= 0 => raw-bit monotone):
//   key = (~bits(s) << 32) | index; ascending == argsort(-s) (R5-R7 proven).
// IoU uses IEEE f32 division in reference expression order (absmax 0.0 R1-R7).
// No cooperative launch (R5: +100us); no spin-waits (only last-arrival ticket).

#define R 512
#define K 81
#define IM_W_MAX 1332.0f   // IM_W - 1
#define IM_H_MAX 799.0f    // IM_H - 1
#define XFORM_CLIP_F 4.135166556742356f  // log(1000/16)
#define NMS_THRESH_F 0.5f
#define SCORE_THRESH_F 0.001f
#define MAX_PER_IMG 100
#define POST_NMS_TOPN 300

// Box transform for (roi r, class k). Value-identical to R1-R7 (absmax 0.0).
__device__ __forceinline__ float4 transform_box(const float* __restrict__ rois,
                                                const float* __restrict__ deltas,
                                                int r, int k) {
    float4 roi = ((const float4*)rois)[r];
    float4 d4  = *(const float4*)(deltas + (size_t)r * (4 * K) + 4 * k);
    float w  = roi.z - roi.x + 1.0f;
    float h  = roi.w - roi.y + 1.0f;
    float cx = roi.x + 0.5f * w;
    float cy = roi.y + 0.5f * h;
    float dx = d4.x / 10.0f;                       // WX
    float dy = d4.y / 10.0f;                       // WY
    float dw = fminf(d4.z / 5.0f, XFORM_CLIP_F);   // WW
    float dh = fminf(d4.w / 5.0f, XFORM_CLIP_F);   // WH
    float pcx = dx * w + cx;
    float pcy = dy * h + cy;
    float pw  = expf(dw) * w;
    float ph  = expf(dh) * h;
    float4 b;
    b.x = fminf(fmaxf(pcx - 0.5f * pw, 0.0f), IM_W_MAX);
    b.y = fminf(fmaxf(pcy - 0.5f * ph, 0.0f), IM_H_MAX);
    b.z = fminf(fmaxf(pcx + 0.5f * pw - 1.0f, 0.0f), IM_W_MAX);
    b.w = fminf(fmaxf(pcy + 0.5f * ph - 1.0f, 0.0f), IM_H_MAX);
    return b;
}

// ---------------------------------------------------------------------------
// 1. Mega-kernel: rank (redundant per block) + bitmatrix word + ticket-sweep.
// ---------------------------------------------------------------------------
__global__ void __launch_bounds__(256)
nms_mega_kernel(const float* __restrict__ rois,
                const float* __restrict__ deltas,
                const float* __restrict__ scores,
                unsigned long long* __restrict__ supT_g,  // [K][8][512]
                float* __restrict__ dists_t,              // [K][R]
                unsigned int* __restrict__ ticket) {      // [K]
    const int b   = blockIdx.x;
    const int k   = b >> 3;
    const int w   = b & 7;
    const int tid = threadIdx.x;

    __shared__ unsigned long long s_key[R];    // 4 KB (keys by orig index)
    __shared__ int    s_order[R];              // 2 KB (order[rank] = orig)
    __shared__ float  s_ssc[R];                // 2 KB (scores in sorted order)
    __shared__ float4 s_sbox[R];               // 8 KB (boxes in sorted order)
    __shared__ float  s_area[R];               // 2 KB
    __shared__ float  s_red[256];              // 1 KB
    __shared__ int    s_winner;

    // ---- Phase 1: scores -> keys + max (2 rois/thread) ----
    const int i0 = tid, i1 = tid + 256;
    const float sc0 = scores[i0 * K + k];      // strided, L2-resident
    const float sc1 = scores[i1 * K + k];
    {
        unsigned int b0 = __float_as_uint(sc0);     // sc >= 0: bits monotone
        unsigned int b1 = __float_as_uint(sc1);
        s_key[i0] = ((unsigned long long)(~b0) << 32) | (unsigned int)i0;
        s_key[i1] = ((unsigned long long)(~b1) << 32) | (unsigned int)i1;
    }
    s_red[tid] = fmaxf(sc0, sc1);
    __syncthreads();
    for (int s = 128; s > 0; s >>= 1) {
        if (tid < s) s_red[tid] = fmaxf(s_red[tid], s_red[tid + s]);
        __syncthreads();
    }
    const bool valid = (k != 0) && (s_red[0] > SCORE_THRESH_F);  // uniform

    if (valid) {
        // ---- Phase 2: stable rank (exact, u64 keys; broadcast LDS scan) ----
        {
            const unsigned long long k0 = s_key[i0], k1 = s_key[i1];
            int c0 = 0, c1 = 0;
            const ulonglong2* kp = (const ulonglong2*)s_key;
            #pragma unroll 8
            for (int j2 = 0; j2 < R / 2; ++j2) {
                ulonglong2 k2 = kp[j2];
                c0 += (k2.x < k0); c0 += (k2.y < k0);
                c1 += (k2.x < k1); c1 += (k2.y < k1);
            }
            s_order[c0] = i0; s_ssc[c0] = sc0;
            s_order[c1] = i1; s_ssc[c1] = sc1;
        }
        __syncthreads();

        // ---- Phase 3: boxes at sorted positions ----
        #pragma unroll
        for (int rep = 0; rep < 2; ++rep) {
            const int rk = tid + rep * 256;
            float4 bx = transform_box(rois, deltas, s_order[rk], k);
            s_sbox[rk] = bx;
            s_area[rk] = (bx.z - bx.x + 1.0f) * (bx.w - bx.y + 1.0f);
        }
        __syncthreads();

        // ---- Phase 4: bitmatrix word w (2 rows/thread), store global ----
        const int jbase = w * 64;
        #pragma unroll
        for (int rep = 0; rep < 2; ++rep) {
            const int i = tid + rep * 256;
            const int d = i - jbase;     // bits jj <= d are j <= i: masked
            unsigned long long mask =
                (d < 0) ? ~0ull : ((d >= 63) ? 0ull : (~0ull << (d + 1)));
            unsigned long long bits = 0ull;
            if (mask) {                  // wave-uniform skip for past waves
                const float4 bi = s_sbox[i];
                const float  ai = s_area[i];
                #pragma unroll 8
                for (int jj = 0; jj < 64; ++jj) {
                    float4 bj = s_sbox[jbase + jj];   // broadcast LDS read
                    float  aj = s_area[jbase + jj];
                    float xx1 = fmaxf(bi.x, bj.x);
                    float yy1 = fmaxf(bi.y, bj.y);
                    float xx2 = fminf(bi.z, bj.z);
                    float yy2 = fminf(bi.w, bj.w);
                    float iw = fmaxf(xx2 - xx1 + 1.0f, 0.0f);
                    float ih = fmaxf(yy2 - yy1 + 1.0f, 0.0f);
                    float inter = iw * ih;
                    float iou = inter / (ai + aj - inter); // IEEE div, ref order
                    bits |= (unsigned long long)(iou > NMS_THRESH_F) << jj;
                }
            }
            supT_g[k * 4096 + w * 512 + i] = bits & mask;  // coalesced u64
        }
    }

    // ---- Phase 5: per-class ticket (deadlock-free last-arrival) ----
    __syncthreads();                      // all supT stores complete in-block
    if (tid == 0) {
        __threadfence();                  // release this block's supT stores
        unsigned int t = atomicAdd(&ticket[k], 1u);
        s_winner = (t == 7u);
    }
    __syncthreads();
    if (!s_winner) return;
    __threadfence();                      // acquire sibling blocks' supT stores

    // ---- Phase 6 (winner only): sweep / zero ----
    if (!valid) {
        #pragma unroll
        for (int rep = 0; rep < 2; ++rep) dists_t[k * R + tid + rep * 256] = 0.0f;
        return;
    }
    if (tid >= 64) return;                // single wave (R7-proven sweep)
    const int l = tid;

    // Scatter data from this block's own LDS rank tables (no global round-trip).
    int   ord[8];
    float ssc[8];
    #pragma unroll
    for (int p = 0; p < 8; ++p) {
        ord[p] = s_order[p * 64 + l];
        ssc[p] = s_ssc[p * 64 + l];
    }

    const unsigned long long* base = supT_g + (size_t)k * 4096;
    unsigned long long rrow[8], rnext[8];
    #pragma unroll
    for (int ww = 0; ww < 8; ++ww) rrow[ww] = base[ww * 512 + l];   // wb=0 rows

    unsigned long long kb[8];
    #pragma unroll
    for (int ww = 0; ww < 8; ++ww) kb[ww] = ~0ull;

    #pragma unroll
    for (int wb = 0; wb < 8; ++wb) {
        if (wb < 7) {                     // prefetch next wb's rows
            #pragma unroll
            for (int ww = 0; ww < 8; ++ww)
                rnext[ww] = (ww > wb) ? base[ww * 512 + (wb + 1) * 64 + l] : 0ull;
        }

        // Intra-block greedy; zero-row lanes can't change state (exact skip).
        const unsigned long long nz = __ballot(rrow[wb] != 0ull);
        unsigned long long cur = kb[wb];
        unsigned long long m = cur & nz;
        while (m) {                       // wave-uniform serial sweep
            int bit = __builtin_ctzll(m);
            const unsigned int r_lo = (unsigned int)(rrow[wb] & 0xffffffffull);
            const unsigned int r_hi = (unsigned int)(rrow[wb] >> 32);
            unsigned long long row =
                ((unsigned long long)(unsigned int)__builtin_amdgcn_readlane((int)r_hi, bit) << 32) |
                 (unsigned long long)(unsigned int)__builtin_amdgcn_readlane((int)r_lo, bit);
            m &= m - 1;
            cur &= ~row;
            m   &= ~row;
        }
        kb[wb] = cur;

        #pragma unroll
        for (int ww = wb + 1; ww < 8; ++ww) {   // inter-block pruning
            unsigned long long contrib = ((cur >> l) & 1ull) ? rrow[ww] : 0ull;
            if (__ballot(contrib != 0ull)) {
                #pragma unroll
                for (int off = 32; off > 0; off >>= 1)
                    contrib |= __shfl_xor(contrib, off, 64);
                kb[ww] &= ~contrib;
            }
        }

        #pragma unroll
        for (int ww = 0; ww < 8; ++ww) rrow[ww] = rnext[ww];
    }

    // cumsum(keep) <= 300 cut, sorted-rank order (uniform, lane-redundant).
    int total = 0;
    #pragma unroll
    for (int ww = 0; ww < 8; ++ww) total += __popcll(kb[ww]);
    if (total > POST_NMS_TOPN) {
        int cnt = 0;
        #pragma unroll
        for (int ww = 0; ww < 8; ++ww) {
            int pc = __popcll(kb[ww]);
            if (cnt + pc <= POST_NMS_TOPN) { cnt += pc; continue; }
            unsigned long long word = kb[ww], outw = 0ull;
            int room = POST_NMS_TOPN - cnt;
            while (room > 0) {
                unsigned long long lsb = word & (~word + 1ull);
                outw |= lsb; word ^= lsb; --room;
            }
            kb[ww] = outw; cnt = POST_NMS_TOPN;
        }
    }

    // Scatter masked scores back to original index order.
    #pragma unroll
    for (int p = 0; p < 8; ++p)
        dists_t[k * R + ord[p]] = ((kb[p] >> l) & 1ull) ? ssc[p] : 0.0f;
}

// ---------------------------------------------------------------------------
// 2. Finalize (R7-proven verbatim): 8 blocks; each computes scores_pre/argmax
//    for all 512 rois (coalesced, redundant), ranks its own 64 rois with
//    8 threads/roi + segmented shfl_xor sum. Exactly 100 winners write.
//    Output (700 floats): [0..499] out(100x5), [500..599] labels, [600..699] top.
// ---------------------------------------------------------------------------
__global__ void __launch_bounds__(512)
finalize_kernel(const float* __restrict__ dists_t,
                const float* __restrict__ rois,
                const float* __restrict__ deltas,
                float* __restrict__ out) {
    const int b = blockIdx.x;      // 0..7 -> rois [b*64, b*64+64)
    const int t = threadIdx.x;
    __shared__ unsigned long long s_key[R];   // 4 KB
    __shared__ int s_arg[R];                  // 2 KB

    // Phase A: per-roi max/first-argmax over K classes (coalesced reads).
    {
        const int r = t;
        float vmax = dists_t[r];   // kk = 0 column (always zeros)
        int arg = 0;
        #pragma unroll 8
        for (int kk = 1; kk < K; ++kk) {
            float v = dists_t[kk * R + r];
            if (v > vmax) { vmax = v; arg = kk; }   // first-occurrence argmax
        }
        unsigned int bits = __float_as_uint(vmax);  // vmax >= 0
        s_key[r] = ((unsigned long long)(~bits) << 32) | (unsigned int)r;
        s_arg[r] = arg;
    }
    __syncthreads();

    // Phase B: rank this block's 64 rois. 8 threads/roi, 64 keys each;
    // chunk-rotated index avoids bank conflicts; order-free sum.
    const int ri = b * 64 + (t >> 3);
    const int c  = t & 7;
    const unsigned long long ki = s_key[ri];
    int cnt = 0;
    #pragma unroll 8
    for (int j = 0; j < 64; ++j) {
        int jj = (j + c * 8) & 63;
        cnt += (s_key[c * 64 + jj] < ki);
    }
    cnt += __shfl_xor(cnt, 1, 64);     // sum within the 8-lane segment
    cnt += __shfl_xor(cnt, 2, 64);
    cnt += __shfl_xor(cnt, 4, 64);

    if (c == 0 && cnt < MAX_PER_IMG) { // exactly 100 winners grid-wide
        float vmax = __uint_as_float(~(unsigned int)(ki >> 32));
        int arg = s_arg[ri];
        bool valid = vmax > SCORE_THRESH_F;
        float4 bx = transform_box(rois, deltas, ri, arg);
        out[cnt * 5 + 0] = valid ? vmax : 0.0f;
        out[cnt * 5 + 1] = valid ? bx.x : 0.0f;
        out[cnt * 5 + 2] = valid ? bx.y : 0.0f;
        out[cnt * 5 + 3] = valid ? bx.z : 0.0f;
        out[cnt * 5 + 4] = valid ? bx.w : 0.0f;
        out[500 + cnt] = (float)arg;   // labels_all
        out[600 + cnt] = (float)ri;    // top
    }
}

// ---------------------------------------------------------------------------
extern "C" void kernel_launch(void* const* d_in, const int* in_sizes, int n_in,
                              void* d_out, int out_size, void* d_ws, size_t ws_size,
                              hipStream_t stream) {
    const float* rois   = (const float*)d_in[0];   // [512,4]
    const float* deltas = (const float*)d_in[1];   // [512,324]
    const float* scores = (const float*)d_in[2];   // [512,81]
    float* out = (float*)d_out;                    // 700 floats

    char* ws = (char*)d_ws;                        // ~2.8 MB used
    unsigned long long* supT_g = (unsigned long long*)(ws + 0);   // 2,654,208 B
    float* dists_t = (float*)(ws + 2654208);                      //   165,888 B
    unsigned int* ticket = (unsigned int*)(ws + 2820096);         //       324 B

    hipMemsetAsync(ticket, 0, K * sizeof(unsigned int), stream);  // ws poisoned
    nms_mega_kernel<<<K * 8, 256, 0, stream>>>(rois, deltas, scores,
                                               supT_g, dists_t, ticket);
    finalize_kernel<<<8, 512, 0, stream>>>(dists_t, rois, deltas, out);
}

// Round 9
// 115.651 us; speedup vs baseline: 1.3187x; 1.3187x over previous
//
#include <hip/hip_runtime.h>
#include <cstdint>
#include <cstddef>

// Mask R-CNN detection post-processing, 3 stream-ordered dispatches:
//   1. rank_boxes (324 x 128, block = class x quarter): u64-key stable rank
//      + sorted boxes/scores/order -> global; zeroes the done-counter.
//   2. bitmatrix (648 x 256, block = class x word): IoU suppression bits with
//      BIT-EXACT banded compare (2*inter vs denom*(1 +/- 2^-22); rare middle
//      band falls back to the verbatim IEEE division) -> global.
//   3. sweep_finalize (89 x 256): blocks 0..80 = single-wave nz-filtered
//      greedy sweep + top-300 cut + scatter, release fence + done++;
//      blocks 81..88 spin-acquire (all 89 blocks co-resident on 256 CUs =>
//      deadlock-free), then distributed u64-key top-100 finalize + output.
// Stable sorts via integer keys (softmax scores >= 0 => raw-bit monotone):
//   key = (~bits(s) << 32) | index; ascending == argsort(-s) (R5-R8 proven).
// NO 648-block device fences (R8: +48us), NO cooperative launch (R5: +100us),
// NO single-CU finalize tail (R6: ~+25us).

#define R 512
#define K 81
#define IM_W_MAX 1332.0f   // IM_W - 1
#define IM_H_MAX 799.0f    // IM_H - 1
#define XFORM_CLIP_F 4.135166556742356f  // log(1000/16)
#define NMS_THRESH_F 0.5f
#define SCORE_THRESH_F 0.001f
#define MAX_PER_IMG 100
#define POST_NMS_TOPN 300

// Box transform for (roi r, class k). Value-identical to R1-R8 (absmax 0.0).
__device__ __forceinline__ float4 transform_box(const float* __restrict__ rois,
                                                const float* __restrict__ deltas,
                                                int r, int k) {
    float4 roi = ((const float4*)rois)[r];
    float4 d4  = *(const float4*)(deltas + (size_t)r * (4 * K) + 4 * k);
    float w  = roi.z - roi.x + 1.0f;
    float h  = roi.w - roi.y + 1.0f;
    float cx = roi.x + 0.5f * w;
    float cy = roi.y + 0.5f * h;
    float dx = d4.x / 10.0f;                       // WX
    float dy = d4.y / 10.0f;                       // WY
    float dw = fminf(d4.z / 5.0f, XFORM_CLIP_F);   // WW
    float dh = fminf(d4.w / 5.0f, XFORM_CLIP_F);   // WH
    float pcx = dx * w + cx;
    float pcy = dy * h + cy;
    float pw  = expf(dw) * w;
    float ph  = expf(dh) * h;
    float4 b;
    b.x = fminf(fmaxf(pcx - 0.5f * pw, 0.0f), IM_W_MAX);
    b.y = fminf(fmaxf(pcy - 0.5f * ph, 0.0f), IM_H_MAX);
    b.z = fminf(fmaxf(pcx + 0.5f * pw - 1.0f, 0.0f), IM_W_MAX);
    b.w = fminf(fmaxf(pcy + 0.5f * ph - 1.0f, 0.0f), IM_H_MAX);
    return b;
}

// ---------------------------------------------------------------------------
// 1. Rank: block = (class k, quarter q). 128 threads; keys for all 512 rois
//    in LDS; each thread ranks one roi of its quarter. 324 blocks (4x spread).
// ---------------------------------------------------------------------------
__global__ void __launch_bounds__(128)
rank_boxes_kernel(const float* __restrict__ rois,
                  const float* __restrict__ deltas,
                  const float* __restrict__ scores,
                  float4* __restrict__ sbox_g,     // [K][R] sorted boxes
                  int* __restrict__ order_g,       // [K][R] order[rank]=orig
                  float* __restrict__ ssc_g,       // [K][R] sorted scores
                  int* __restrict__ valid_g,       // [K]
                  unsigned int* __restrict__ done) {
    const int b = blockIdx.x;
    const int k = b >> 2, q = b & 3;
    const int tid = threadIdx.x;
    __shared__ unsigned long long s_key[R];        // 4 KB
    __shared__ float s_red[128];

    if (b == 0 && tid == 0) *done = 0u;            // init for sweep_finalize

    float m = -1.0f;
    #pragma unroll
    for (int p = 0; p < 4; ++p) {                  // keys for all 512 rois
        const int i = p * 128 + tid;
        float sc = scores[i * K + k];              // strided, L2-resident
        unsigned int bits = __float_as_uint(sc);   // sc >= 0: bits monotone
        s_key[i] = ((unsigned long long)(~bits) << 32) | (unsigned int)i;
        m = fmaxf(m, sc);
    }
    s_red[tid] = m;
    __syncthreads();
    for (int s = 64; s > 0; s >>= 1) {
        if (tid < s) s_red[tid] = fmaxf(s_red[tid], s_red[tid + s]);
        __syncthreads();
    }
    const bool valid = (k != 0) && (s_red[0] > SCORE_THRESH_F);  // uniform
    if (q == 0 && tid == 0) valid_g[k] = valid;
    if (!valid) return;

    const int ri = q * 128 + tid;                  // this thread's roi
    const unsigned long long ki = s_key[ri];
    int cnt = 0;                                   // exact stable rank
    const ulonglong2* kp = (const ulonglong2*)s_key;  // uniform -> broadcast
    #pragma unroll 8
    for (int j2 = 0; j2 < R / 2; ++j2) {
        ulonglong2 k2 = kp[j2];
        cnt += (k2.x < ki);
        cnt += (k2.y < ki);
    }
    sbox_g[k * R + cnt]  = transform_box(rois, deltas, ri, k);
    order_g[k * R + cnt] = ri;
    ssc_g[k * R + cnt]   = __uint_as_float(~(unsigned int)(ki >> 32));
}

// ---------------------------------------------------------------------------
// 2. Bitmatrix: block = (class k, word w). supT_g[k][w][i] bit jj set iff
//    j = w*64+jj > i and IoU(i,j) > 0.5 (sorted order).
//    Banded compare (BIT-EXACT): RN(inter/denom) > 0.5 <=> 2*inter >
//    denom*(1+2^-24) exactly. hi = denom*(1+2^-22) >= that bound even after
//    rounding; lo = denom*(1-2^-22) <= it. Outside [lo,hi]: decided without
//    div. Inside (rare): verbatim IEEE `inter/denom > 0.5f` (exec-skipped).
// ---------------------------------------------------------------------------
__global__ void __launch_bounds__(256)
bitmatrix_kernel(const float4* __restrict__ sbox_g,
                 const int* __restrict__ valid_g,
                 unsigned long long* __restrict__ supT_g) {
    const int b = blockIdx.x;
    const int k = b >> 3;
    const int w = b & 7;
    const int tid = threadIdx.x;
    if (!valid_g[k]) return;       // sweep handles invalid k

    __shared__ float4 s_sbox[R];   // 8 KB
    __shared__ float  s_area[R];   // 2 KB
    for (int i = tid; i < R; i += 256) {
        float4 bx = sbox_g[k * R + i];
        s_sbox[i] = bx;
        s_area[i] = (bx.z - bx.x + 1.0f) * (bx.w - bx.y + 1.0f);
    }
    __syncthreads();

    const int jbase = w * 64;
    #pragma unroll
    for (int rep = 0; rep < 2; ++rep) {
        const int i = tid + rep * 256;
        const int d = i - jbase;   // bits jj <= d are j <= i: masked out
        unsigned long long mask =
            (d < 0) ? ~0ull : ((d >= 63) ? 0ull : (~0ull << (d + 1)));
        unsigned long long bits = 0ull;
        if (mask) {                // wave-uniform skip for fully-past waves
            const float4 bi = s_sbox[i];
            const float  ai = s_area[i];
            #pragma unroll 8
            for (int jj = 0; jj < 64; ++jj) {
                float4 bj = s_sbox[jbase + jj];   // broadcast LDS read
                float  aj = s_area[jbase + jj];
                float xx1 = fmaxf(bi.x, bj.x);
                float yy1 = fmaxf(bi.y, bj.y);
                float xx2 = fminf(bi.z, bj.z);
                float yy2 = fminf(bi.w, bj.w);
                float iw = fmaxf(xx2 - xx1 + 1.0f, 0.0f);
                float ih = fmaxf(yy2 - yy1 + 1.0f, 0.0f);
                float inter = iw * ih;
                float denom = ai + aj - inter;     // > 0 always (areas >= 1)
                float two_i = inter + inter;       // exact (x2)
                float hi = denom * 1.0000002f;     // RN -> 1+2^-22 exactly
                float lo = denom * 0.99999976f;    // RN -> 1-2^-22 exactly
                bool sup = two_i > hi;
                if (!sup && !(two_i < lo)) {       // rare band: exact IEEE
                    sup = (inter / denom) > NMS_THRESH_F;  // ref expression
                }
                bits |= (unsigned long long)sup << jj;
            }
        }
        supT_g[k * 4096 + w * 512 + i] = bits & mask;    // coalesced u64
    }
}

// ---------------------------------------------------------------------------
// 3. Sweep (blocks 0..80) + finalize (blocks 81..88, spin-gated).
//    89 blocks x 256 threads: all co-resident on 256 CUs => spin is safe.
// ---------------------------------------------------------------------------
__global__ void __launch_bounds__(256)
sweep_finalize_kernel(const unsigned long long* __restrict__ supT_g,
                      const int* __restrict__ order_g,
                      const float* __restrict__ ssc_g,
                      const int* __restrict__ valid_g,
                      const float* __restrict__ rois,
                      const float* __restrict__ deltas,
                      float* __restrict__ dists_t,     // [K][R]
                      unsigned int* __restrict__ done,
                      float* __restrict__ out) {
    const int b   = blockIdx.x;
    const int tid = threadIdx.x;

    if (b < K) {
        // ================= SWEEP (R7-proven, single wave) =================
        if (tid >= 64) return;            // waves 1-3 idle
        const int k = b, l = tid;

        if (valid_g[k]) {
            int   ord[8];
            float ssc[8];
            #pragma unroll
            for (int p = 0; p < 8; ++p) {     // prefetch scatter data
                ord[p] = order_g[k * R + p * 64 + l];
                ssc[p] = ssc_g[k * R + p * 64 + l];
            }

            const unsigned long long* base = supT_g + (size_t)k * 4096;
            unsigned long long rrow[8], rnext[8];
            #pragma unroll
            for (int ww = 0; ww < 8; ++ww) rrow[ww] = base[ww * 512 + l];

            unsigned long long kb[8];
            #pragma unroll
            for (int ww = 0; ww < 8; ++ww) kb[ww] = ~0ull;

            #pragma unroll
            for (int wb = 0; wb < 8; ++wb) {
                if (wb < 7) {                 // prefetch next wb's rows
                    #pragma unroll
                    for (int ww = 0; ww < 8; ++ww)
                        rnext[ww] = (ww > wb) ? base[ww * 512 + (wb + 1) * 64 + l] : 0ull;
                }
                // Intra-block greedy; zero-row lanes can't change state.
                const unsigned long long nz = __ballot(rrow[wb] != 0ull);
                unsigned long long cur = kb[wb];
                unsigned long long m = cur & nz;
                while (m) {                   // wave-uniform serial sweep
                    int bit = __builtin_ctzll(m);
                    const unsigned int r_lo = (unsigned int)(rrow[wb] & 0xffffffffull);
                    const unsigned int r_hi = (unsigned int)(rrow[wb] >> 32);
                    unsigned long long row =
                        ((unsigned long long)(unsigned int)__builtin_amdgcn_readlane((int)r_hi, bit) << 32) |
                         (unsigned long long)(unsigned int)__builtin_amdgcn_readlane((int)r_lo, bit);
                    m &= m - 1;
                    cur &= ~row;
                    m   &= ~row;
                }
                kb[wb] = cur;

                #pragma unroll
                for (int ww = wb + 1; ww < 8; ++ww) {   // inter-block pruning
                    unsigned long long contrib = ((cur >> l) & 1ull) ? rrow[ww] : 0ull;
                    if (__ballot(contrib != 0ull)) {
                        #pragma unroll
                        for (int off = 32; off > 0; off >>= 1)
                            contrib |= __shfl_xor(contrib, off, 64);
                        kb[ww] &= ~contrib;
                    }
                }
                #pragma unroll
                for (int ww = 0; ww < 8; ++ww) rrow[ww] = rnext[ww];
            }

            // cumsum(keep) <= 300 cut, sorted-rank order (lane-redundant).
            int total = 0;
            #pragma unroll
            for (int ww = 0; ww < 8; ++ww) total += __popcll(kb[ww]);
            if (total > POST_NMS_TOPN) {
                int cnt = 0;
                #pragma unroll
                for (int ww = 0; ww < 8; ++ww) {
                    int pc = __popcll(kb[ww]);
                    if (cnt + pc <= POST_NMS_TOPN) { cnt += pc; continue; }
                    unsigned long long word = kb[ww], outw = 0ull;
                    int room = POST_NMS_TOPN - cnt;
                    while (room > 0) {
                        unsigned long long lsb = word & (~word + 1ull);
                        outw |= lsb; word ^= lsb; --room;
                    }
                    kb[ww] = outw; cnt = POST_NMS_TOPN;
                }
            }
            #pragma unroll
            for (int p = 0; p < 8; ++p)       // scatter to original order
                dists_t[k * R + ord[p]] = ((kb[p] >> l) & 1ull) ? ssc[p] : 0.0f;
        } else {
            #pragma unroll
            for (int p = 0; p < 8; ++p) dists_t[k * R + p * 64 + l] = 0.0f;
        }

        if (l == 0) {
            __threadfence();                  // release dists_t (81 fences ok)
            atomicAdd(done, 1u);
        }
        return;
    }

    // ================= FINALIZE (blocks 81..88, spin-gated) =================
    __shared__ unsigned long long s_key[R];   // 4 KB
    __shared__ int s_arg[R];                  // 2 KB
    const int fb = b - K;                     // 0..7 -> rois [fb*64, fb*64+64)

    if (tid == 0) {
        while (__hip_atomic_load(done, __ATOMIC_ACQUIRE,
                                 __HIP_MEMORY_SCOPE_AGENT) < (unsigned)K)
            __builtin_amdgcn_s_sleep(8);
    }
    __syncthreads();                          // all threads see dists_t

    // Phase A: per-roi max/first-argmax over K classes (2 rois/thread).
    #pragma unroll
    for (int rep = 0; rep < 2; ++rep) {
        const int r = tid + rep * 256;
        float vmax = dists_t[r];              // kk = 0 column (always zeros)
        int arg = 0;
        #pragma unroll 8
        for (int kk = 1; kk < K; ++kk) {
            float v = dists_t[kk * R + r];    // coalesced
            if (v > vmax) { vmax = v; arg = kk; }   // first-occurrence argmax
        }
        unsigned int bits = __float_as_uint(vmax);  // vmax >= 0
        s_key[r] = ((unsigned long long)(~bits) << 32) | (unsigned int)r;
        s_arg[r] = arg;
    }
    __syncthreads();

    // Phase B: rank this block's 64 rois; 4 threads/roi, 128 keys each.
    // Lanes with equal c read the same address -> LDS broadcast.
    const int ri = fb * 64 + (tid >> 2);
    const int c  = tid & 3;
    const unsigned long long ki = s_key[ri];
    int cnt = 0;
    #pragma unroll 8
    for (int j = 0; j < 128; ++j)
        cnt += (s_key[c * 128 + j] < ki);
    cnt += __shfl_xor(cnt, 1, 64);            // sum the 4-lane segment
    cnt += __shfl_xor(cnt, 2, 64);

    if (c == 0 && cnt < MAX_PER_IMG) {        // exactly 100 winners grid-wide
        float vmax = __uint_as_float(~(unsigned int)(ki >> 32));
        int arg = s_arg[ri];
        bool valid = vmax > SCORE_THRESH_F;
        float4 bx = transform_box(rois, deltas, ri, arg);
        out[cnt * 5 + 0] = valid ? vmax : 0.0f;
        out[cnt * 5 + 1] = valid ? bx.x : 0.0f;
        out[cnt * 5 + 2] = valid ? bx.y : 0.0f;
        out[cnt * 5 + 3] = valid ? bx.z : 0.0f;
        out[cnt * 5 + 4] = valid ? bx.w : 0.0f;
        out[500 + cnt] = (float)arg;          // labels_all
        out[600 + cnt] = (float)ri;           // top
    }
}

// ---------------------------------------------------------------------------
extern "C" void kernel_launch(void* const* d_in, const int* in_sizes, int n_in,
                              void* d_out, int out_size, void* d_ws, size_t ws_size,
                              hipStream_t stream) {
    const float* rois   = (const float*)d_in[0];   // [512,4]
    const float* deltas = (const float*)d_in[1];   // [512,324]
    const float* scores = (const float*)d_in[2];   // [512,81]
    float* out = (float*)d_out;                    // 700 floats

    char* ws = (char*)d_ws;                        // ~3.7 MB used
    float4* sbox_g  = (float4*)(ws + 0);                              // 663,552 B
    int*    order_g = (int*)   (ws + 663552);                         // 165,888 B
    float*  ssc_g   = (float*) (ws + 829440);                         // 165,888 B
    int*    valid_g = (int*)   (ws + 995328);                         //     512 B
    float*  dists_t = (float*) (ws + 995840);                         // 165,888 B
    unsigned long long* supT_g = (unsigned long long*)(ws + 1161728); // 2,654,208 B
    unsigned int* done = (unsigned int*)(ws + 3815936);               //       4 B

    rank_boxes_kernel    <<<K * 4, 128, 0, stream>>>(rois, deltas, scores,
                                                     sbox_g, order_g, ssc_g,
                                                     valid_g, done);
    bitmatrix_kernel     <<<K * 8, 256, 0, stream>>>(sbox_g, valid_g, supT_g);
    sweep_finalize_kernel<<<K + 8, 256, 0, stream>>>(supT_g, order_g, ssc_g,
                                                     valid_g, rois, deltas,
                                                     dists_t, done, out);
}

// Round 10
// 109.300 us; speedup vs baseline: 1.3954x; 1.0581x over previous
//
#include <hip/hip_runtime.h>
#include <cstdint>
#include <cstddef>

// Mask R-CNN detection post-processing, 4 stream-ordered kernels (R7 structure,
// proven fastest at 111.3us, + R9's bit-exact banded IoU compare):
//   1. rank_boxes (81 x 512):  u64-key stable rank + sorted boxes + validity
//   2. bitmatrix  (648 x 256): IoU suppression bits, banded compare (hot path
//                              add+2mul+2cmp; rare band -> verbatim IEEE div)
//   3. sweep      (81 x 64):   single-wave nz-filtered greedy sweep + top-300
//   4. finalize   (8 x 512):   per-row max/argmax + distributed top-100 + out
// Stable sorts via integer keys (softmax scores >= 0 => raw-bit monotone):
//   key = (~bits(s) << 32) | index; ascending == argsort(-s) (R5-R9 proven).
// Decision-exact IoU band: RN(inter/denom) > 0.5 <=> 2*inter > denom*(1+2^-24);
// outside denom*(1 +/- 2^-22) the compare decides; inside falls back to the
// reference expression (absmax 0.0 in R9).
// Avoided (measured regressions): cooperative grid.sync (R5 +100us),
// 648-block device fences (R8 +48us), single-CU finalize tail (R6 ~+25us),
// spin-gated sweep+finalize merge & 4x-spread rank (R9 +4us).

#define R 512
#define K 81
#define IM_W_MAX 1332.0f   // IM_W - 1
#define IM_H_MAX 799.0f    // IM_H - 1
#define XFORM_CLIP_F 4.135166556742356f  // log(1000/16)
#define NMS_THRESH_F 0.5f
#define SCORE_THRESH_F 0.001f
#define MAX_PER_IMG 100
#define POST_NMS_TOPN 300

// Box transform for (roi r, class k). Value-identical to R1-R9 (absmax 0.0).
__device__ __forceinline__ float4 transform_box(const float* __restrict__ rois,
                                                const float* __restrict__ deltas,
                                                int r, int k) {
    float4 roi = ((const float4*)rois)[r];
    float4 d4  = *(const float4*)(deltas + (size_t)r * (4 * K) + 4 * k);
    float w  = roi.z - roi.x + 1.0f;
    float h  = roi.w - roi.y + 1.0f;
    float cx = roi.x + 0.5f * w;
    float cy = roi.y + 0.5f * h;
    float dx = d4.x / 10.0f;                       // WX
    float dy = d4.y / 10.0f;                       // WY
    float dw = fminf(d4.z / 5.0f, XFORM_CLIP_F);   // WW
    float dh = fminf(d4.w / 5.0f, XFORM_CLIP_F);   // WH
    float pcx = dx * w + cx;
    float pcy = dy * h + cy;
    float pw  = expf(dw) * w;
    float ph  = expf(dh) * h;
    float4 b;
    b.x = fminf(fmaxf(pcx - 0.5f * pw, 0.0f), IM_W_MAX);
    b.y = fminf(fmaxf(pcy - 0.5f * ph, 0.0f), IM_H_MAX);
    b.z = fminf(fmaxf(pcx + 0.5f * pw - 1.0f, 0.0f), IM_W_MAX);
    b.w = fminf(fmaxf(pcy + 0.5f * ph - 1.0f, 0.0f), IM_H_MAX);
    return b;
}

// ---------------------------------------------------------------------------
// 1. Per-class u64-key stable rank + sorted boxes/scores + validity
//    (R6/R7-proven verbatim).
// ---------------------------------------------------------------------------
__global__ void __launch_bounds__(512)
rank_boxes_kernel(const float* __restrict__ rois,
                  const float* __restrict__ deltas,
                  const float* __restrict__ scores,
                  float4* __restrict__ sbox_g,     // [K][R] sorted boxes
                  int* __restrict__ order_g,       // [K][R] order[rank]=orig
                  float* __restrict__ ssc_g,       // [K][R] sorted scores
                  int* __restrict__ valid_g) {     // [K]
    const int k = blockIdx.x, tid = threadIdx.x;
    __shared__ unsigned long long s_key[R];        // 4 KB
    __shared__ float s_red[R];                     // 2 KB

    const float sc = scores[tid * K + k];          // strided, L2-resident
    {
        unsigned int bits = __float_as_uint(sc);   // sc >= 0: bits monotone
        s_key[tid] = ((unsigned long long)(~bits) << 32) | (unsigned int)tid;
    }
    s_red[tid] = sc;
    __syncthreads();
    for (int s = 256; s > 0; s >>= 1) {
        if (tid < s) s_red[tid] = fmaxf(s_red[tid], s_red[tid + s]);
        __syncthreads();
    }
    const bool valid = (k != 0) && (s_red[0] > SCORE_THRESH_F);  // uniform
    if (tid == 0) valid_g[k] = valid;
    if (!valid) return;

    const unsigned long long ki = s_key[tid];
    int cnt = 0;                                   // exact stable rank
    const ulonglong2* kp = (const ulonglong2*)s_key;  // uniform j2 -> broadcast
    #pragma unroll 8
    for (int j2 = 0; j2 < R / 2; ++j2) {
        ulonglong2 k2 = kp[j2];
        cnt += (k2.x < ki);
        cnt += (k2.y < ki);
    }
    sbox_g[k * R + cnt]  = transform_box(rois, deltas, tid, k);
    order_g[k * R + cnt] = tid;
    ssc_g[k * R + cnt]   = sc;
}

// ---------------------------------------------------------------------------
// 2. Bitmatrix: block = (class k, word w). supT_g[k][w][i] bit jj set iff
//    j = w*64+jj > i and IoU(i,j) > 0.5 (sorted order). Banded compare
//    (R9-proven bit-exact): hot path has no division.
// ---------------------------------------------------------------------------
__global__ void __launch_bounds__(256)
bitmatrix_kernel(const float4* __restrict__ sbox_g,
                 const int* __restrict__ valid_g,
                 unsigned long long* __restrict__ supT_g) {
    const int b = blockIdx.x;
    const int k = b >> 3;
    const int w = b & 7;
    const int tid = threadIdx.x;
    if (!valid_g[k]) return;       // sweep handles invalid k

    __shared__ float4 s_sbox[R];   // 8 KB
    __shared__ float  s_area[R];   // 2 KB
    for (int i = tid; i < R; i += 256) {
        float4 bx = sbox_g[k * R + i];
        s_sbox[i] = bx;
        s_area[i] = (bx.z - bx.x + 1.0f) * (bx.w - bx.y + 1.0f);
    }
    __syncthreads();

    const int jbase = w * 64;
    #pragma unroll
    for (int rep = 0; rep < 2; ++rep) {
        const int i = tid + rep * 256;
        const int d = i - jbase;   // bits jj <= d are j <= i: masked out
        unsigned long long mask =
            (d < 0) ? ~0ull : ((d >= 63) ? 0ull : (~0ull << (d + 1)));
        unsigned long long bits = 0ull;
        if (mask) {                // wave-uniform skip for fully-past waves
            const float4 bi = s_sbox[i];
            const float  ai = s_area[i];
            #pragma unroll 8
            for (int jj = 0; jj < 64; ++jj) {
                float4 bj = s_sbox[jbase + jj];   // broadcast LDS read
                float  aj = s_area[jbase + jj];
                float xx1 = fmaxf(bi.x, bj.x);
                float yy1 = fmaxf(bi.y, bj.y);
                float xx2 = fminf(bi.z, bj.z);
                float yy2 = fminf(bi.w, bj.w);
                float iw = fmaxf(xx2 - xx1 + 1.0f, 0.0f);
                float ih = fmaxf(yy2 - yy1 + 1.0f, 0.0f);
                float inter = iw * ih;
                float denom = ai + aj - inter;     // > 0 always (areas >= 1)
                float two_i = inter + inter;       // exact (x2)
                float hi = denom * 1.0000002f;     // 1+2^-22: sure-true bound
                float lo = denom * 0.99999976f;    // 1-2^-22: sure-false bound
                bool sup = two_i > hi;
                if (!sup && !(two_i < lo)) {       // rare band: exact IEEE
                    sup = (inter / denom) > NMS_THRESH_F;  // ref expression
                }
                bits |= (unsigned long long)sup << jj;
            }
        }
        supT_g[k * 4096 + w * 512 + i] = bits & mask;    // coalesced u64
    }
}

// ---------------------------------------------------------------------------
// 3. Sweep: ONE WAVE per class (R7-proven verbatim). Rows direct from global
//    (prefetched, coalesced); nz-filtered serial greedy; top-300 cut; scatter.
// ---------------------------------------------------------------------------
__global__ void __launch_bounds__(64)
sweep_kernel(const unsigned long long* __restrict__ supT_g,
             const int* __restrict__ order_g,
             const float* __restrict__ ssc_g,
             const int* __restrict__ valid_g,
             float* __restrict__ dists_t) {       // [K][R]
    const int k = blockIdx.x;
    const int l = threadIdx.x;                    // lane 0..63

    if (!valid_g[k]) {
        #pragma unroll
        for (int p = 0; p < 8; ++p) dists_t[k * R + p * 64 + l] = 0.0f;
        return;
    }

    // Prefetch scatter data (overlaps the sweep).
    int   ord[8];
    float ssc[8];
    #pragma unroll
    for (int p = 0; p < 8; ++p) {
        ord[p] = order_g[k * R + p * 64 + l];
        ssc[p] = ssc_g[k * R + p * 64 + l];
    }

    const unsigned long long* base = supT_g + (size_t)k * 4096;
    unsigned long long rrow[8], rnext[8];
    #pragma unroll
    for (int w = 0; w < 8; ++w) rrow[w] = base[w * 512 + l];   // wb=0 rows

    unsigned long long kb[8];
    #pragma unroll
    for (int w = 0; w < 8; ++w) kb[w] = ~0ull;

    #pragma unroll
    for (int wb = 0; wb < 8; ++wb) {
        if (wb < 7) {                  // prefetch next wb's rows
            #pragma unroll
            for (int w = 0; w < 8; ++w)
                rnext[w] = (w > wb) ? base[w * 512 + (wb + 1) * 64 + l] : 0ull;
        }

        // Intra-block greedy: zero-row lanes can't change state (exact skip).
        const unsigned long long nz = __ballot(rrow[wb] != 0ull);
        unsigned long long cur = kb[wb];
        unsigned long long m = cur & nz;
        while (m) {                    // wave-uniform serial sweep
            int bit = __builtin_ctzll(m);
            const unsigned int r_lo = (unsigned int)(rrow[wb] & 0xffffffffull);
            const unsigned int r_hi = (unsigned int)(rrow[wb] >> 32);
            unsigned long long row =
                ((unsigned long long)(unsigned int)__builtin_amdgcn_readlane((int)r_hi, bit) << 32) |
                 (unsigned long long)(unsigned int)__builtin_amdgcn_readlane((int)r_lo, bit);
            m &= m - 1;
            cur &= ~row;
            m   &= ~row;
        }
        kb[wb] = cur;

        // Inter-block pruning: OR of kept rows' future words (ballot-guarded).
        #pragma unroll
        for (int w = wb + 1; w < 8; ++w) {
            unsigned long long contrib = ((cur >> l) & 1ull) ? rrow[w] : 0ull;
            if (__ballot(contrib != 0ull)) {
                #pragma unroll
                for (int off = 32; off > 0; off >>= 1)
                    contrib |= __shfl_xor(contrib, off, 64);
                kb[w] &= ~contrib;
            }
        }

        #pragma unroll
        for (int w = 0; w < 8; ++w) rrow[w] = rnext[w];
    }

    // cumsum(keep) <= 300 cut, sorted-rank order (uniform, lane-redundant).
    int total = 0;
    #pragma unroll
    for (int w = 0; w < 8; ++w) total += __popcll(kb[w]);
    if (total > POST_NMS_TOPN) {
        int cnt = 0;
        #pragma unroll
        for (int w = 0; w < 8; ++w) {
            int pc = __popcll(kb[w]);
            if (cnt + pc <= POST_NMS_TOPN) { cnt += pc; continue; }
            unsigned long long word = kb[w], outw = 0ull;
            int room = POST_NMS_TOPN - cnt;
            while (room > 0) {
                unsigned long long lsb = word & (~word + 1ull);
                outw |= lsb; word ^= lsb; --room;
            }
            kb[w] = outw; cnt = POST_NMS_TOPN;
        }
    }

    // Scatter masked scores back to original index order.
    #pragma unroll
    for (int p = 0; p < 8; ++p)
        dists_t[k * R + ord[p]] = ((kb[p] >> l) & 1ull) ? ssc[p] : 0.0f;
}

// ---------------------------------------------------------------------------
// 4. Finalize (R7-proven verbatim): 8 blocks; each computes scores_pre/argmax
//    for all 512 rois (coalesced, redundant), ranks its own 64 rois with
//    8 threads/roi + segmented shfl_xor sum. Exactly 100 winners write.
//    Output (700 floats): [0..499] out(100x5), [500..599] labels, [600..699] top.
// ---------------------------------------------------------------------------
__global__ void __launch_bounds__(512)
finalize_kernel(const float* __restrict__ dists_t,
                const float* __restrict__ rois,
                const float* __restrict__ deltas,
                float* __restrict__ out) {
    const int b = blockIdx.x;      // 0..7 -> rois [b*64, b*64+64)
    const int t = threadIdx.x;
    __shared__ unsigned long long s_key[R];   // 4 KB
    __shared__ int s_arg[R];                  // 2 KB

    // Phase A: per-roi max/first-argmax over K classes (coalesced reads).
    {
        const int r = t;
        float vmax = dists_t[r];   // kk = 0 column (always zeros)
        int arg = 0;
        #pragma unroll 8
        for (int kk = 1; kk < K; ++kk) {
            float v = dists_t[kk * R + r];
            if (v > vmax) { vmax = v; arg = kk; }   // first-occurrence argmax
        }
        unsigned int bits = __float_as_uint(vmax);  // vmax >= 0
        s_key[r] = ((unsigned long long)(~bits) << 32) | (unsigned int)r;
        s_arg[r] = arg;
    }
    __syncthreads();

    // Phase B: rank this block's 64 rois. 8 threads/roi, 64 keys each;
    // chunk-rotated index avoids bank conflicts; order-free sum.
    const int ri = b * 64 + (t >> 3);
    const int c  = t & 7;
    const unsigned long long ki = s_key[ri];
    int cnt = 0;
    #pragma unroll 8
    for (int j = 0; j < 64; ++j) {
        int jj = (j + c * 8) & 63;
        cnt += (s_key[c * 64 + jj] < ki);
    }
    cnt += __shfl_xor(cnt, 1, 64);     // sum within the 8-lane segment
    cnt += __shfl_xor(cnt, 2, 64);
    cnt += __shfl_xor(cnt, 4, 64);

    if (c == 0 && cnt < MAX_PER_IMG) { // exactly 100 winners grid-wide
        float vmax = __uint_as_float(~(unsigned int)(ki >> 32));
        int arg = s_arg[ri];
        bool valid = vmax > SCORE_THRESH_F;
        float4 bx = transform_box(rois, deltas, ri, arg);
        out[cnt * 5 + 0] = valid ? vmax : 0.0f;
        out[cnt * 5 + 1] = valid ? bx.x : 0.0f;
        out[cnt * 5 + 2] = valid ? bx.y : 0.0f;
        out[cnt * 5 + 3] = valid ? bx.z : 0.0f;
        out[cnt * 5 + 4] = valid ? bx.w : 0.0f;
        out[500 + cnt] = (float)arg;   // labels_all
        out[600 + cnt] = (float)ri;    // top
    }
}

// ---------------------------------------------------------------------------
extern "C" void kernel_launch(void* const* d_in, const int* in_sizes, int n_in,
                              void* d_out, int out_size, void* d_ws, size_t ws_size,
                              hipStream_t stream) {
    const float* rois   = (const float*)d_in[0];   // [512,4]
    const float* deltas = (const float*)d_in[1];   // [512,324]
    const float* scores = (const float*)d_in[2];   // [512,81]
    float* out = (float*)d_out;                    // 700 floats

    char* ws = (char*)d_ws;                        // ~3.7 MB used
    float4* sbox_g  = (float4*)(ws + 0);                              // 663,552 B
    int*    order_g = (int*)   (ws + 663552);                         // 165,888 B
    float*  ssc_g   = (float*) (ws + 829440);                         // 165,888 B
    int*    valid_g = (int*)   (ws + 995328);                         //     512 B
    float*  dists_t = (float*) (ws + 995840);                         // 165,888 B
    unsigned long long* supT_g = (unsigned long long*)(ws + 1161728); // 2,654,208 B

    rank_boxes_kernel<<<K, 512, 0, stream>>>(rois, deltas, scores,
                                             sbox_g, order_g, ssc_g, valid_g);
    bitmatrix_kernel <<<K * 8, 256, 0, stream>>>(sbox_g, valid_g, supT_g);
    sweep_kernel     <<<K, 64, 0, stream>>>(supT_g, order_g, ssc_g, valid_g, dists_t);
    finalize_kernel  <<<8, 512, 0, stream>>>(dists_t, rois, deltas, out);
}